// Round 1
// baseline (746.128 us; speedup 1.0000x reference)
//
#include <hip/hip_runtime.h>

// Problem constants
#define NNODES 65536
#define NEDGES 524288

typedef short bf16x8 __attribute__((ext_vector_type(8)));
typedef float f32x4 __attribute__((ext_vector_type(4)));

// Packed-weight fragment offsets (in bf16 elements) within the weight region of d_ws.
// Fragment layout per matrix (K x NC): [n_tile][k_tile][lane][8], 512 bf16 per fragment.
#define OF_MW1 0        // 320x256: KT=10, NT=16 -> 81920
#define OF_MW2 81920    // 256x256: KT=8,  NT=16 -> 65536
#define OF_MW3 147456   // 256x128: KT=8,  NT=8  -> 32768
#define OF_UW1 180224   // 384x256: KT=12, NT=16 -> 98304
#define OF_UW2 278528   // 256x256: KT=8,  NT=16 -> 65536
#define OF_UW3 344064   // 256x128: KT=8,  NT=8  -> 32768

#define WS_SUMMED_BYTES ((size_t)NNODES * 128 * 4)

__device__ __forceinline__ unsigned short f2bf(float x) {
  unsigned int u = __float_as_uint(x);
  return (unsigned short)((u + 0x7FFFu + ((u >> 16) & 1u)) >> 16);  // RNE
}

__device__ __forceinline__ void cvt_store8(unsigned short* p, float4 a, float4 b) {
  union { unsigned short u[8]; bf16x8 v; } t;
  t.u[0] = f2bf(a.x); t.u[1] = f2bf(a.y); t.u[2] = f2bf(a.z); t.u[3] = f2bf(a.w);
  t.u[4] = f2bf(b.x); t.u[5] = f2bf(b.y); t.u[6] = f2bf(b.z); t.u[7] = f2bf(b.w);
  *reinterpret_cast<bf16x8*>(p) = t.v;
}

// 64-row tile GEMM: A (64 x 32*KT, bf16 in LDS, row stride lda elems) times
// W fragments (pre-packed, this wave's N-range), accumulating 4 M-tiles x NTW N-tiles.
template <int KT, int NTW>
__device__ __forceinline__ void gemm_tile64(const unsigned short* A, const int lda,
                                            const unsigned short* Wf,
                                            f32x4 (&acc)[4][NTW], const int lane) {
  const int ar = lane & 15;
  const int ak = (lane >> 4) << 3;
  for (int kt = 0; kt < KT; ++kt) {
    bf16x8 a[4];
#pragma unroll
    for (int m = 0; m < 4; ++m)
      a[m] = *reinterpret_cast<const bf16x8*>(&A[(m * 16 + ar) * lda + kt * 32 + ak]);
#pragma unroll
    for (int n = 0; n < NTW; ++n) {
      bf16x8 b = *reinterpret_cast<const bf16x8*>(&Wf[(n * KT + kt) * 512 + lane * 8]);
#pragma unroll
      for (int m = 0; m < 4; ++m)
        acc[m][n] = __builtin_amdgcn_mfma_f32_16x16x32_bf16(a[m], b, acc[m][n], 0, 0, 0);
    }
  }
}

// Convert all six weight matrices into MFMA B-fragment order (bf16).
__global__ void prep_weights(const float* __restrict__ mW1, const float* __restrict__ mW2,
                             const float* __restrict__ mW3, const float* __restrict__ uW1,
                             const float* __restrict__ uW2, const float* __restrict__ uW3,
                             unsigned short* __restrict__ wf) {
  const int f = blockIdx.x;
  const int lane = threadIdx.x;
  const float* W; int NC, KT, fl, base;
  if (f < 160)      { W = mW1; NC = 256; KT = 10; fl = f;       base = OF_MW1; }
  else if (f < 288) { W = mW2; NC = 256; KT = 8;  fl = f - 160; base = OF_MW2; }
  else if (f < 352) { W = mW3; NC = 128; KT = 8;  fl = f - 288; base = OF_MW3; }
  else if (f < 544) { W = uW1; NC = 256; KT = 12; fl = f - 352; base = OF_UW1; }
  else if (f < 672) { W = uW2; NC = 256; KT = 8;  fl = f - 544; base = OF_UW2; }
  else              { W = uW3; NC = 128; KT = 8;  fl = f - 672; base = OF_UW3; }
  const int n_t = fl / KT;
  const int k_t = fl % KT;
  const int col = n_t * 16 + (lane & 15);
  const int krow = k_t * 32 + ((lane >> 4) << 3);
  unsigned short* dst = wf + base + (size_t)fl * 512 + lane * 8;
#pragma unroll
  for (int e = 0; e < 8; ++e) dst[e] = f2bf(W[(size_t)(krow + e) * NC + col]);
}

// Message MLP + scatter-add. 64 edges per workgroup, 4 waves.
__global__ __launch_bounds__(256, 2) void msg_kernel(
    const float* __restrict__ ns, const float* __restrict__ edg,
    const int* __restrict__ verts, const unsigned short* __restrict__ wf,
    const float* __restrict__ mb1, const float* __restrict__ mb2,
    const float* __restrict__ mb3, float* __restrict__ summed) {
  extern __shared__ unsigned short smem[];
  unsigned short* Xs = smem;                       // [64][328] bf16 (320 + 8 pad)
  unsigned short* Hs = smem + 64 * 328;            // [64][264] bf16 (256 + 8 pad)
  int* vl = (int*)(smem + 64 * 328 + 64 * 264);    // [2][64]

  const int tid = threadIdx.x;
  const int lane = tid & 63;
  const int w = tid >> 6;
  const int e0 = blockIdx.x * 64;

  if (tid < 64) {
    vl[tid] = verts[(size_t)(e0 + tid) * 2];
    vl[64 + tid] = verts[(size_t)(e0 + tid) * 2 + 1];
  }
  __syncthreads();

  // Gather [node_i | node_j | edge] -> Xs (bf16)
  {
    const int r = tid >> 4;
    const int c = tid & 15;
#pragma unroll
    for (int p = 0; p < 4; ++p) {
      const int row = p * 16 + r;
      const float4* s0 = reinterpret_cast<const float4*>(ns + (size_t)vl[row] * 128 + c * 8);
      cvt_store8(&Xs[row * 328 + c * 8], s0[0], s0[1]);
      const float4* s1 = reinterpret_cast<const float4*>(ns + (size_t)vl[64 + row] * 128 + c * 8);
      cvt_store8(&Xs[row * 328 + 128 + c * 8], s1[0], s1[1]);
      if (c < 8) {
        const float4* s2 = reinterpret_cast<const float4*>(edg + (size_t)(e0 + row) * 64 + c * 8);
        cvt_store8(&Xs[row * 328 + 256 + c * 8], s2[0], s2[1]);
      }
    }
  }
  __syncthreads();

  const int cw = lane & 15;
  const int rq = (lane >> 4) * 4;

  // Layer 1: 320 -> 256, relu. Each wave: 64 output cols.
  {
    f32x4 acc[4][4];
#pragma unroll
    for (int m = 0; m < 4; ++m)
#pragma unroll
      for (int n = 0; n < 4; ++n)
#pragma unroll
        for (int i = 0; i < 4; ++i) acc[m][n][i] = 0.0f;
    gemm_tile64<10, 4>(Xs, 328, wf + OF_MW1 + (size_t)(w * 4) * 10 * 512, acc, lane);
#pragma unroll
    for (int n = 0; n < 4; ++n) {
      const int col = w * 64 + n * 16 + cw;
      const float bias = mb1[col];
#pragma unroll
      for (int m = 0; m < 4; ++m)
#pragma unroll
        for (int q = 0; q < 4; ++q) {
          const int row = m * 16 + rq + q;
          Hs[row * 264 + col] = f2bf(fmaxf(acc[m][n][q] + bias, 0.0f));
        }
    }
  }
  __syncthreads();

  // Layer 2: 256 -> 256, relu, in-place on Hs.
  {
    f32x4 acc[4][4];
#pragma unroll
    for (int m = 0; m < 4; ++m)
#pragma unroll
      for (int n = 0; n < 4; ++n)
#pragma unroll
        for (int i = 0; i < 4; ++i) acc[m][n][i] = 0.0f;
    gemm_tile64<8, 4>(Hs, 264, wf + OF_MW2 + (size_t)(w * 4) * 8 * 512, acc, lane);
    __syncthreads();  // all reads of Hs done before overwrite
#pragma unroll
    for (int n = 0; n < 4; ++n) {
      const int col = w * 64 + n * 16 + cw;
      const float bias = mb2[col];
#pragma unroll
      for (int m = 0; m < 4; ++m)
#pragma unroll
        for (int q = 0; q < 4; ++q) {
          const int row = m * 16 + rq + q;
          Hs[row * 264 + col] = f2bf(fmaxf(acc[m][n][q] + bias, 0.0f));
        }
    }
  }
  __syncthreads();

  // Layer 3: 256 -> 128, scatter-add into summed for both endpoints.
  {
    f32x4 acc[4][2];
#pragma unroll
    for (int m = 0; m < 4; ++m)
#pragma unroll
      for (int n = 0; n < 2; ++n)
#pragma unroll
        for (int i = 0; i < 4; ++i) acc[m][n][i] = 0.0f;
    gemm_tile64<8, 2>(Hs, 264, wf + OF_MW3 + (size_t)(w * 2) * 8 * 512, acc, lane);
#pragma unroll
    for (int n = 0; n < 2; ++n) {
      const int col = w * 32 + n * 16 + cw;
      const float bias = mb3[col];
#pragma unroll
      for (int m = 0; m < 4; ++m)
#pragma unroll
        for (int q = 0; q < 4; ++q) {
          const int row = m * 16 + rq + q;
          const float v = acc[m][n][q] + bias;
          unsafeAtomicAdd(&summed[(size_t)vl[row] * 128 + col], v);
          unsafeAtomicAdd(&summed[(size_t)vl[64 + row] * 128 + col], v);
        }
    }
  }
}

// Update MLP: 64 nodes per workgroup, 8 waves. attention[n] = ns[n] - ns[n^2048].
__global__ __launch_bounds__(512, 2) void upd_kernel(
    const float* __restrict__ ns, const float* __restrict__ summed,
    const unsigned short* __restrict__ wf, const float* __restrict__ ub1,
    const float* __restrict__ ub2, const float* __restrict__ ub3,
    float* __restrict__ out) {
  extern __shared__ unsigned short smem[];
  unsigned short* Xs = smem;             // [64][392] bf16 (384 + 8 pad)
  unsigned short* Hs = smem + 64 * 392;  // [64][264] bf16

  const int tid = threadIdx.x;
  const int lane = tid & 63;
  const int w = tid >> 6;
  const int n0 = blockIdx.x * 64;

  // Gather [node | summed | node - node^2048] -> Xs (bf16)
  for (int i = tid; i < 1024; i += 512) {
    const int row = i >> 4;
    const int c = (i & 15) * 8;
    const int n = n0 + row;
    const float4* sA = reinterpret_cast<const float4*>(ns + (size_t)n * 128 + c);
    const float4 a0 = sA[0], a1 = sA[1];
    cvt_store8(&Xs[row * 392 + c], a0, a1);
    const float4* sS = reinterpret_cast<const float4*>(summed + (size_t)n * 128 + c);
    cvt_store8(&Xs[row * 392 + 128 + c], sS[0], sS[1]);
    const float4* sP = reinterpret_cast<const float4*>(ns + (size_t)(n ^ 2048) * 128 + c);
    const float4 p0 = sP[0], p1 = sP[1];
    float4 d0, d1;
    d0.x = a0.x - p0.x; d0.y = a0.y - p0.y; d0.z = a0.z - p0.z; d0.w = a0.w - p0.w;
    d1.x = a1.x - p1.x; d1.y = a1.y - p1.y; d1.z = a1.z - p1.z; d1.w = a1.w - p1.w;
    cvt_store8(&Xs[row * 392 + 256 + c], d0, d1);
  }
  __syncthreads();

  const int cw = lane & 15;
  const int rq = (lane >> 4) * 4;

  // Layer 1: 384 -> 256, relu. Each wave: 32 output cols.
  {
    f32x4 acc[4][2];
#pragma unroll
    for (int m = 0; m < 4; ++m)
#pragma unroll
      for (int n = 0; n < 2; ++n)
#pragma unroll
        for (int i = 0; i < 4; ++i) acc[m][n][i] = 0.0f;
    gemm_tile64<12, 2>(Xs, 392, wf + OF_UW1 + (size_t)(w * 2) * 12 * 512, acc, lane);
#pragma unroll
    for (int n = 0; n < 2; ++n) {
      const int col = w * 32 + n * 16 + cw;
      const float bias = ub1[col];
#pragma unroll
      for (int m = 0; m < 4; ++m)
#pragma unroll
        for (int q = 0; q < 4; ++q) {
          const int row = m * 16 + rq + q;
          Hs[row * 264 + col] = f2bf(fmaxf(acc[m][n][q] + bias, 0.0f));
        }
    }
  }
  __syncthreads();

  // Layer 2: 256 -> 256, relu, in-place on Hs.
  {
    f32x4 acc[4][2];
#pragma unroll
    for (int m = 0; m < 4; ++m)
#pragma unroll
      for (int n = 0; n < 2; ++n)
#pragma unroll
        for (int i = 0; i < 4; ++i) acc[m][n][i] = 0.0f;
    gemm_tile64<8, 2>(Hs, 264, wf + OF_UW2 + (size_t)(w * 2) * 8 * 512, acc, lane);
    __syncthreads();
#pragma unroll
    for (int n = 0; n < 2; ++n) {
      const int col = w * 32 + n * 16 + cw;
      const float bias = ub2[col];
#pragma unroll
      for (int m = 0; m < 4; ++m)
#pragma unroll
        for (int q = 0; q < 4; ++q) {
          const int row = m * 16 + rq + q;
          Hs[row * 264 + col] = f2bf(fmaxf(acc[m][n][q] + bias, 0.0f));
        }
    }
  }
  __syncthreads();

  // Layer 3: 256 -> 128 -> out (fp32). Each wave: 16 output cols.
  {
    f32x4 acc[4][1];
#pragma unroll
    for (int m = 0; m < 4; ++m)
#pragma unroll
      for (int i = 0; i < 4; ++i) acc[m][0][i] = 0.0f;
    gemm_tile64<8, 1>(Hs, 264, wf + OF_UW3 + (size_t)w * 8 * 512, acc, lane);
    const int col = w * 16 + cw;
    const float bias = ub3[col];
#pragma unroll
    for (int m = 0; m < 4; ++m)
#pragma unroll
      for (int q = 0; q < 4; ++q) {
        const int row = m * 16 + rq + q;
        out[(size_t)(n0 + row) * 128 + col] = acc[m][0][q] + bias;
      }
  }
}

extern "C" void kernel_launch(void* const* d_in, const int* in_sizes, int n_in,
                              void* d_out, int out_size, void* d_ws, size_t ws_size,
                              hipStream_t stream) {
  const float* ns   = (const float*)d_in[0];
  const float* edg  = (const float*)d_in[1];
  const int* verts  = (const int*)d_in[2];
  const float* mW1  = (const float*)d_in[3];
  const float* mb1  = (const float*)d_in[4];
  const float* mW2  = (const float*)d_in[5];
  const float* mb2  = (const float*)d_in[6];
  const float* mW3  = (const float*)d_in[7];
  const float* mb3  = (const float*)d_in[8];
  const float* uW1  = (const float*)d_in[9];
  const float* ub1  = (const float*)d_in[10];
  const float* uW2  = (const float*)d_in[11];
  const float* ub2  = (const float*)d_in[12];
  const float* uW3  = (const float*)d_in[13];
  const float* ub3  = (const float*)d_in[14];
  float* out = (float*)d_out;

  float* summed = (float*)d_ws;
  unsigned short* wf = (unsigned short*)((char*)d_ws + WS_SUMMED_BYTES);

  // summed must be zero every call (ws is poisoned once, never re-poisoned).
  hipMemsetAsync(summed, 0, WS_SUMMED_BYTES, stream);
  prep_weights<<<736, 64, 0, stream>>>(mW1, mW2, mW3, uW1, uW2, uW3, wf);

  const int msg_lds = (64 * 328 + 64 * 264) * 2 + 128 * 4;
  msg_kernel<<<NEDGES / 64, 256, msg_lds, stream>>>(ns, edg, verts, wf, mb1, mb2, mb3, summed);

  const int upd_lds = (64 * 392 + 64 * 264) * 2;
  upd_kernel<<<NNODES / 64, 512, upd_lds, stream>>>(ns, summed, wf, ub1, ub2, ub3, out);
}

// Round 2
// 726.653 us; speedup vs baseline: 1.0268x; 1.0268x over previous
//
#include <hip/hip_runtime.h>

// Problem constants
#define NNODES 65536
#define NEDGES 524288

typedef short bf16x8 __attribute__((ext_vector_type(8)));
typedef float f32x4 __attribute__((ext_vector_type(4)));

// Packed-weight fragment offsets (in bf16 elements) within the weight region of d_ws.
// Fragment layout per matrix (K x NC): [n_tile][k_tile][lane][8], 512 bf16 per fragment.
#define OF_MW1 0        // 320x256: KT=10, NT=16 -> 81920
#define OF_MW2 81920    // 256x256: KT=8,  NT=16 -> 65536
#define OF_MW3 147456   // 256x128: KT=8,  NT=8  -> 32768
#define OF_UW1 180224   // 384x256: KT=12, NT=16 -> 98304
#define OF_UW2 278528   // 256x256: KT=8,  NT=16 -> 65536
#define OF_UW3 344064   // 256x128: KT=8,  NT=8  -> 32768

#define WS_SUMMED_BYTES ((size_t)NNODES * 128 * 4)

__device__ __forceinline__ unsigned short f2bf(float x) {
  unsigned int u = __float_as_uint(x);
  return (unsigned short)((u + 0x7FFFu + ((u >> 16) & 1u)) >> 16);  // RNE
}

__device__ __forceinline__ void cvt_store8(unsigned short* p, float4 a, float4 b) {
  union { unsigned short u[8]; bf16x8 v; } t;
  t.u[0] = f2bf(a.x); t.u[1] = f2bf(a.y); t.u[2] = f2bf(a.z); t.u[3] = f2bf(a.w);
  t.u[4] = f2bf(b.x); t.u[5] = f2bf(b.y); t.u[6] = f2bf(b.z); t.u[7] = f2bf(b.w);
  *reinterpret_cast<bf16x8*>(p) = t.v;
}

// 64-row tile GEMM: A (64 x 32*KT, bf16 in LDS, row stride lda elems) times
// W fragments (pre-packed, this wave's N-range), accumulating 4 M-tiles x NTW N-tiles.
template <int KT, int NTW>
__device__ __forceinline__ void gemm_tile64(const unsigned short* A, const int lda,
                                            const unsigned short* Wf,
                                            f32x4 (&acc)[4][NTW], const int lane) {
  const int ar = lane & 15;
  const int ak = (lane >> 4) << 3;
#pragma unroll
  for (int kt = 0; kt < KT; ++kt) {
    bf16x8 a[4];
#pragma unroll
    for (int m = 0; m < 4; ++m)
      a[m] = *reinterpret_cast<const bf16x8*>(&A[(m * 16 + ar) * lda + kt * 32 + ak]);
#pragma unroll
    for (int n = 0; n < NTW; ++n) {
      bf16x8 b = *reinterpret_cast<const bf16x8*>(&Wf[(n * KT + kt) * 512 + lane * 8]);
#pragma unroll
      for (int m = 0; m < 4; ++m)
        acc[m][n] = __builtin_amdgcn_mfma_f32_16x16x32_bf16(a[m], b, acc[m][n], 0, 0, 0);
    }
  }
}

// Convert all six weight matrices into MFMA B-fragment order (bf16).
__global__ void prep_weights(const float* __restrict__ mW1, const float* __restrict__ mW2,
                             const float* __restrict__ mW3, const float* __restrict__ uW1,
                             const float* __restrict__ uW2, const float* __restrict__ uW3,
                             unsigned short* __restrict__ wf) {
  const int f = blockIdx.x;
  const int lane = threadIdx.x;
  const float* W; int NC, KT, fl, base;
  if (f < 160)      { W = mW1; NC = 256; KT = 10; fl = f;       base = OF_MW1; }
  else if (f < 288) { W = mW2; NC = 256; KT = 8;  fl = f - 160; base = OF_MW2; }
  else if (f < 352) { W = mW3; NC = 128; KT = 8;  fl = f - 288; base = OF_MW3; }
  else if (f < 544) { W = uW1; NC = 256; KT = 12; fl = f - 352; base = OF_UW1; }
  else if (f < 672) { W = uW2; NC = 256; KT = 8;  fl = f - 544; base = OF_UW2; }
  else              { W = uW3; NC = 128; KT = 8;  fl = f - 672; base = OF_UW3; }
  const int n_t = fl / KT;
  const int k_t = fl % KT;
  const int col = n_t * 16 + (lane & 15);
  const int krow = k_t * 32 + ((lane >> 4) << 3);
  unsigned short* dst = wf + base + (size_t)fl * 512 + lane * 8;
#pragma unroll
  for (int e = 0; e < 8; ++e) dst[e] = f2bf(W[(size_t)(krow + e) * NC + col]);
}

// Message MLP + scatter-add. 64 edges per workgroup, 4 waves, single LDS buffer
// (H layers written back into the X buffer) -> 42.5 KB LDS -> 3 blocks/CU.
__global__ __launch_bounds__(256, 3) void msg_kernel(
    const float* __restrict__ ns, const float* __restrict__ edg,
    const int* __restrict__ verts, const unsigned short* __restrict__ wf,
    const float* __restrict__ mb1, const float* __restrict__ mb2,
    const float* __restrict__ mb3, float* __restrict__ summed) {
  extern __shared__ unsigned short smem[];
  unsigned short* Xs = smem;               // [64][328] bf16; X cols 0..319, then H 0..255
  int* vl = (int*)(smem + 64 * 328);       // [128] interleaved: vl[2r+p] = verts[e0+r][p]

  const int tid = threadIdx.x;
  const int lane = tid & 63;
  const int w = tid >> 6;
  const int e0 = blockIdx.x * 64;

  // Phase 1: vertex indices (coalesced) + edge features -> Xs cols 256..319
  if (tid < 128) vl[tid] = verts[(size_t)e0 * 2 + tid];
#pragma unroll
  for (int i = tid; i < 512; i += 256) {
    const int row = i >> 3;
    const int c = (i & 7) * 8;
    const float4* s2 = reinterpret_cast<const float4*>(edg + (size_t)(e0 + row) * 64 + c);
    cvt_store8(&Xs[row * 328 + 256 + c], s2[0], s2[1]);
  }
  __syncthreads();

  // Phase 2: gather node_i | node_j -> Xs cols 0..255
  {
    const int r = tid >> 4;
    const int c = (tid & 15) * 8;
#pragma unroll
    for (int p = 0; p < 4; ++p) {
      const int row = p * 16 + r;
      const float4* s0 = reinterpret_cast<const float4*>(ns + (size_t)vl[2 * row] * 128 + c);
      cvt_store8(&Xs[row * 328 + c], s0[0], s0[1]);
      const float4* s1 = reinterpret_cast<const float4*>(ns + (size_t)vl[2 * row + 1] * 128 + c);
      cvt_store8(&Xs[row * 328 + 128 + c], s1[0], s1[1]);
    }
  }
  __syncthreads();

  const int cw = lane & 15;
  const int rq = (lane >> 4) * 4;

  // Layer 1: 320 -> 256, relu. Each wave: 64 output cols. H written back into Xs.
  {
    f32x4 acc[4][4];
#pragma unroll
    for (int m = 0; m < 4; ++m)
#pragma unroll
      for (int n = 0; n < 4; ++n)
#pragma unroll
        for (int i = 0; i < 4; ++i) acc[m][n][i] = 0.0f;
    gemm_tile64<10, 4>(Xs, 328, wf + OF_MW1 + (size_t)(w * 4) * 10 * 512, acc, lane);
    __syncthreads();  // all reads of X done before overwrite
#pragma unroll
    for (int n = 0; n < 4; ++n) {
      const int col = w * 64 + n * 16 + cw;
      const float bias = mb1[col];
#pragma unroll
      for (int m = 0; m < 4; ++m)
#pragma unroll
        for (int q = 0; q < 4; ++q) {
          const int row = m * 16 + rq + q;
          Xs[row * 328 + col] = f2bf(fmaxf(acc[m][n][q] + bias, 0.0f));
        }
    }
  }
  __syncthreads();

  // Layer 2: 256 -> 256, relu, in-place on Xs.
  {
    f32x4 acc[4][4];
#pragma unroll
    for (int m = 0; m < 4; ++m)
#pragma unroll
      for (int n = 0; n < 4; ++n)
#pragma unroll
        for (int i = 0; i < 4; ++i) acc[m][n][i] = 0.0f;
    gemm_tile64<8, 4>(Xs, 328, wf + OF_MW2 + (size_t)(w * 4) * 8 * 512, acc, lane);
    __syncthreads();
#pragma unroll
    for (int n = 0; n < 4; ++n) {
      const int col = w * 64 + n * 16 + cw;
      const float bias = mb2[col];
#pragma unroll
      for (int m = 0; m < 4; ++m)
#pragma unroll
        for (int q = 0; q < 4; ++q) {
          const int row = m * 16 + rq + q;
          Xs[row * 328 + col] = f2bf(fmaxf(acc[m][n][q] + bias, 0.0f));
        }
    }
  }
  __syncthreads();

  // Layer 3: 256 -> 128, scatter-add into summed for both endpoints.
  {
    f32x4 acc[4][2];
#pragma unroll
    for (int m = 0; m < 4; ++m)
#pragma unroll
      for (int n = 0; n < 2; ++n)
#pragma unroll
        for (int i = 0; i < 4; ++i) acc[m][n][i] = 0.0f;
    gemm_tile64<8, 2>(Xs, 328, wf + OF_MW3 + (size_t)(w * 2) * 8 * 512, acc, lane);
#pragma unroll
    for (int n = 0; n < 2; ++n) {
      const int col = w * 32 + n * 16 + cw;
      const float bias = mb3[col];
#pragma unroll
      for (int m = 0; m < 4; ++m)
#pragma unroll
        for (int q = 0; q < 4; ++q) {
          const int row = m * 16 + rq + q;
          const float v = acc[m][n][q] + bias;
          unsafeAtomicAdd(&summed[(size_t)vl[2 * row] * 128 + col], v);
          unsafeAtomicAdd(&summed[(size_t)vl[2 * row + 1] * 128 + col], v);
        }
    }
  }
}

// Update MLP: 64 nodes per workgroup, 4 waves, single LDS buffer (50 KB -> 3 blocks/CU).
// attention[n] = ns[n] - ns[n^2048].
__global__ __launch_bounds__(256, 3) void upd_kernel(
    const float* __restrict__ ns, const float* __restrict__ summed,
    const unsigned short* __restrict__ wf, const float* __restrict__ ub1,
    const float* __restrict__ ub2, const float* __restrict__ ub3,
    float* __restrict__ out) {
  extern __shared__ unsigned short smem[];
  unsigned short* Xs = smem;  // [64][392]; X cols 0..383, then H 0..255

  const int tid = threadIdx.x;
  const int lane = tid & 63;
  const int w = tid >> 6;
  const int n0 = blockIdx.x * 64;

  // Gather [node | summed | node - node^2048] -> Xs (bf16)
  for (int i = tid; i < 1024; i += 256) {
    const int row = i >> 4;
    const int c = (i & 15) * 8;
    const int n = n0 + row;
    const float4* sA = reinterpret_cast<const float4*>(ns + (size_t)n * 128 + c);
    const float4 a0 = sA[0], a1 = sA[1];
    cvt_store8(&Xs[row * 392 + c], a0, a1);
    const float4* sS = reinterpret_cast<const float4*>(summed + (size_t)n * 128 + c);
    cvt_store8(&Xs[row * 392 + 128 + c], sS[0], sS[1]);
    const float4* sP = reinterpret_cast<const float4*>(ns + (size_t)(n ^ 2048) * 128 + c);
    const float4 p0 = sP[0], p1 = sP[1];
    float4 d0, d1;
    d0.x = a0.x - p0.x; d0.y = a0.y - p0.y; d0.z = a0.z - p0.z; d0.w = a0.w - p0.w;
    d1.x = a1.x - p1.x; d1.y = a1.y - p1.y; d1.z = a1.z - p1.z; d1.w = a1.w - p1.w;
    cvt_store8(&Xs[row * 392 + 256 + c], d0, d1);
  }
  __syncthreads();

  const int cw = lane & 15;
  const int rq = (lane >> 4) * 4;

  // Layer 1: 384 -> 256, relu. Each wave: 64 output cols. H back into Xs.
  {
    f32x4 acc[4][4];
#pragma unroll
    for (int m = 0; m < 4; ++m)
#pragma unroll
      for (int n = 0; n < 4; ++n)
#pragma unroll
        for (int i = 0; i < 4; ++i) acc[m][n][i] = 0.0f;
    gemm_tile64<12, 4>(Xs, 392, wf + OF_UW1 + (size_t)(w * 4) * 12 * 512, acc, lane);
    __syncthreads();
#pragma unroll
    for (int n = 0; n < 4; ++n) {
      const int col = w * 64 + n * 16 + cw;
      const float bias = ub1[col];
#pragma unroll
      for (int m = 0; m < 4; ++m)
#pragma unroll
        for (int q = 0; q < 4; ++q) {
          const int row = m * 16 + rq + q;
          Xs[row * 392 + col] = f2bf(fmaxf(acc[m][n][q] + bias, 0.0f));
        }
    }
  }
  __syncthreads();

  // Layer 2: 256 -> 256, relu, in-place on Xs.
  {
    f32x4 acc[4][4];
#pragma unroll
    for (int m = 0; m < 4; ++m)
#pragma unroll
      for (int n = 0; n < 4; ++n)
#pragma unroll
        for (int i = 0; i < 4; ++i) acc[m][n][i] = 0.0f;
    gemm_tile64<8, 4>(Xs, 392, wf + OF_UW2 + (size_t)(w * 4) * 8 * 512, acc, lane);
    __syncthreads();
#pragma unroll
    for (int n = 0; n < 4; ++n) {
      const int col = w * 64 + n * 16 + cw;
      const float bias = ub2[col];
#pragma unroll
      for (int m = 0; m < 4; ++m)
#pragma unroll
        for (int q = 0; q < 4; ++q) {
          const int row = m * 16 + rq + q;
          Xs[row * 392 + col] = f2bf(fmaxf(acc[m][n][q] + bias, 0.0f));
        }
    }
  }
  __syncthreads();

  // Layer 3: 256 -> 128 -> out (fp32). Each wave: 32 output cols.
  {
    f32x4 acc[4][2];
#pragma unroll
    for (int m = 0; m < 4; ++m)
#pragma unroll
      for (int n = 0; n < 2; ++n)
#pragma unroll
        for (int i = 0; i < 4; ++i) acc[m][n][i] = 0.0f;
    gemm_tile64<8, 2>(Xs, 392, wf + OF_UW3 + (size_t)(w * 2) * 8 * 512, acc, lane);
#pragma unroll
    for (int n = 0; n < 2; ++n) {
      const int col = w * 32 + n * 16 + cw;
      const float bias = ub3[col];
#pragma unroll
      for (int m = 0; m < 4; ++m)
#pragma unroll
        for (int q = 0; q < 4; ++q) {
          const int row = m * 16 + rq + q;
          out[(size_t)(n0 + row) * 128 + col] = acc[m][n][q] + bias;
        }
    }
  }
}

extern "C" void kernel_launch(void* const* d_in, const int* in_sizes, int n_in,
                              void* d_out, int out_size, void* d_ws, size_t ws_size,
                              hipStream_t stream) {
  const float* ns   = (const float*)d_in[0];
  const float* edg  = (const float*)d_in[1];
  const int* verts  = (const int*)d_in[2];
  const float* mW1  = (const float*)d_in[3];
  const float* mb1  = (const float*)d_in[4];
  const float* mW2  = (const float*)d_in[5];
  const float* mb2  = (const float*)d_in[6];
  const float* mW3  = (const float*)d_in[7];
  const float* mb3  = (const float*)d_in[8];
  const float* uW1  = (const float*)d_in[9];
  const float* ub1  = (const float*)d_in[10];
  const float* uW2  = (const float*)d_in[11];
  const float* ub2  = (const float*)d_in[12];
  const float* uW3  = (const float*)d_in[13];
  const float* ub3  = (const float*)d_in[14];
  float* out = (float*)d_out;

  float* summed = (float*)d_ws;
  unsigned short* wf = (unsigned short*)((char*)d_ws + WS_SUMMED_BYTES);

  // summed must be zero every call (ws is poisoned once, never re-poisoned).
  hipMemsetAsync(summed, 0, WS_SUMMED_BYTES, stream);
  prep_weights<<<736, 64, 0, stream>>>(mW1, mW2, mW3, uW1, uW2, uW3, wf);

  const int msg_lds = 64 * 328 * 2 + 128 * 4;  // 42496 B -> 3 blocks/CU
  msg_kernel<<<NEDGES / 64, 256, msg_lds, stream>>>(ns, edg, verts, wf, mb1, mb2, mb3, summed);

  const int upd_lds = 64 * 392 * 2;            // 50176 B -> 3 blocks/CU
  upd_kernel<<<NNODES / 64, 256, upd_lds, stream>>>(ns, summed, wf, ub1, ub2, ub3, out);
}

// Round 3
// 559.878 us; speedup vs baseline: 1.3327x; 1.2979x over previous
//
#include <hip/hip_runtime.h>

// Problem constants
#define NNODES 65536
#define NEDGES 524288

typedef short bf16x8 __attribute__((ext_vector_type(8)));
typedef float f32x4 __attribute__((ext_vector_type(4)));

// Packed-weight fragment offsets (in bf16 elements) within the weight region.
// Fragment layout per matrix (K x NC): [n_tile][k_tile][lane][8], 512 bf16 per fragment.
#define OF_MW1 0        // 320x256: KT=10, NT=16 -> 81920
#define OF_MW2 81920    // 256x256: KT=8,  NT=16 -> 65536
#define OF_MW3 147456   // 256x128: KT=8,  NT=8  -> 32768
#define OF_UW1 180224   // 384x256: KT=12, NT=16 -> 98304
#define OF_UW2 278528   // 256x256: KT=8,  NT=16 -> 65536
#define OF_UW3 344064   // 256x128: KT=8,  NT=8  -> 32768
#define WF_BYTES (376832 * 2)

// Big-workspace layout (CSR path)
#define WS_MSGS_BYTES ((size_t)NEDGES * 128 * 2)          // 134217728 (bf16)
#define WS_EIDX_OFF   WS_MSGS_BYTES
#define WS_EIDX_BYTES ((size_t)NNODES * 64 * 4)           // 16777216
#define WS_CNT_OFF    (WS_EIDX_OFF + WS_EIDX_BYTES)
#define WS_CNT_BYTES  ((size_t)NNODES * 4)                // 262144
#define WS_WF_OFF     (WS_CNT_OFF + WS_CNT_BYTES)
#define WS_NEED       (WS_WF_OFF + WF_BYTES)

// Fallback layout (atomic path)
#define WS_SUMMED_BYTES ((size_t)NNODES * 128 * 4)

__device__ __forceinline__ unsigned short f2bf(float x) {
  unsigned int u = __float_as_uint(x);
  return (unsigned short)((u + 0x7FFFu + ((u >> 16) & 1u)) >> 16);  // RNE
}

__device__ __forceinline__ float bf2f(short s) {
  return __uint_as_float((unsigned int)(unsigned short)s << 16);
}

__device__ __forceinline__ void cvt_store8(unsigned short* p, float4 a, float4 b) {
  union { unsigned short u[8]; bf16x8 v; } t;
  t.u[0] = f2bf(a.x); t.u[1] = f2bf(a.y); t.u[2] = f2bf(a.z); t.u[3] = f2bf(a.w);
  t.u[4] = f2bf(b.x); t.u[5] = f2bf(b.y); t.u[6] = f2bf(b.z); t.u[7] = f2bf(b.w);
  *reinterpret_cast<bf16x8*>(p) = t.v;
}

// 64-row tile GEMM: A (64 x 32*KT, bf16 in LDS, row stride lda elems) times
// W fragments (pre-packed, this wave's N-range), accumulating 4 M-tiles x NTW N-tiles.
template <int KT, int NTW>
__device__ __forceinline__ void gemm_tile64(const unsigned short* A, const int lda,
                                            const unsigned short* Wf,
                                            f32x4 (&acc)[4][NTW], const int lane) {
  const int ar = lane & 15;
  const int ak = (lane >> 4) << 3;
#pragma unroll
  for (int kt = 0; kt < KT; ++kt) {
    bf16x8 a[4];
#pragma unroll
    for (int m = 0; m < 4; ++m)
      a[m] = *reinterpret_cast<const bf16x8*>(&A[(m * 16 + ar) * lda + kt * 32 + ak]);
#pragma unroll
    for (int n = 0; n < NTW; ++n) {
      bf16x8 b = *reinterpret_cast<const bf16x8*>(&Wf[(n * KT + kt) * 512 + lane * 8]);
#pragma unroll
      for (int m = 0; m < 4; ++m)
        acc[m][n] = __builtin_amdgcn_mfma_f32_16x16x32_bf16(a[m], b, acc[m][n], 0, 0, 0);
    }
  }
}

// Convert all six weight matrices into MFMA B-fragment order (bf16).
__global__ void prep_weights(const float* __restrict__ mW1, const float* __restrict__ mW2,
                             const float* __restrict__ mW3, const float* __restrict__ uW1,
                             const float* __restrict__ uW2, const float* __restrict__ uW3,
                             unsigned short* __restrict__ wf) {
  const int f = blockIdx.x;
  const int lane = threadIdx.x;
  const float* W; int NC, KT, fl, base;
  if (f < 160)      { W = mW1; NC = 256; KT = 10; fl = f;       base = OF_MW1; }
  else if (f < 288) { W = mW2; NC = 256; KT = 8;  fl = f - 160; base = OF_MW2; }
  else if (f < 352) { W = mW3; NC = 128; KT = 8;  fl = f - 288; base = OF_MW3; }
  else if (f < 544) { W = uW1; NC = 256; KT = 12; fl = f - 352; base = OF_UW1; }
  else if (f < 672) { W = uW2; NC = 256; KT = 8;  fl = f - 544; base = OF_UW2; }
  else              { W = uW3; NC = 128; KT = 8;  fl = f - 672; base = OF_UW3; }
  const int n_t = fl / KT;
  const int k_t = fl % KT;
  const int col = n_t * 16 + (lane & 15);
  const int krow = k_t * 32 + ((lane >> 4) << 3);
  unsigned short* dst = wf + base + (size_t)fl * 512 + lane * 8;
#pragma unroll
  for (int e = 0; e < 8; ++e) dst[e] = f2bf(W[(size_t)(krow + e) * NC + col]);
}

// Bucket fill: one thread per endpoint entry (2E total).
__global__ void fill_csr(const int* __restrict__ verts, int* __restrict__ cnt,
                         int* __restrict__ eidx) {
  const int k = blockIdx.x * 256 + threadIdx.x;
  const int v = verts[k];
  const int slot = atomicAdd(&cnt[v], 1);
  if (slot < 64) eidx[(size_t)v * 64 + slot] = k >> 1;  // message row = edge id
}

// Message MLP. 64 edges per workgroup, 4 waves, single LDS buffer -> 3 blocks/CU.
// ATOMIC=true: scatter-add into summed (fallback). ATOMIC=false: stream bf16 msgs.
template <bool ATOMIC>
__global__ __launch_bounds__(256, 3) void msg_kernel(
    const float* __restrict__ ns, const float* __restrict__ edg,
    const int* __restrict__ verts, const unsigned short* __restrict__ wf,
    const float* __restrict__ mb1, const float* __restrict__ mb2,
    const float* __restrict__ mb3, float* __restrict__ summed,
    unsigned short* __restrict__ msgs) {
  extern __shared__ unsigned short smem[];
  unsigned short* Xs = smem;               // [64][328] bf16; X cols 0..319, then H 0..255
  int* vl = (int*)(smem + 64 * 328);       // [128] interleaved: vl[2r+p] = verts[e0+r][p]

  const int tid = threadIdx.x;
  const int lane = tid & 63;
  const int w = tid >> 6;
  const int e0 = blockIdx.x * 64;

  // Phase 1: vertex indices (coalesced) + edge features -> Xs cols 256..319
  if (tid < 128) vl[tid] = verts[(size_t)e0 * 2 + tid];
#pragma unroll
  for (int i = tid; i < 512; i += 256) {
    const int row = i >> 3;
    const int c = (i & 7) * 8;
    const float4* s2 = reinterpret_cast<const float4*>(edg + (size_t)(e0 + row) * 64 + c);
    cvt_store8(&Xs[row * 328 + 256 + c], s2[0], s2[1]);
  }
  __syncthreads();

  // Phase 2: gather node_i | node_j -> Xs cols 0..255
  {
    const int r = tid >> 4;
    const int c = (tid & 15) * 8;
#pragma unroll
    for (int p = 0; p < 4; ++p) {
      const int row = p * 16 + r;
      const float4* s0 = reinterpret_cast<const float4*>(ns + (size_t)vl[2 * row] * 128 + c);
      cvt_store8(&Xs[row * 328 + c], s0[0], s0[1]);
      const float4* s1 = reinterpret_cast<const float4*>(ns + (size_t)vl[2 * row + 1] * 128 + c);
      cvt_store8(&Xs[row * 328 + 128 + c], s1[0], s1[1]);
    }
  }
  __syncthreads();

  const int cw = lane & 15;
  const int rq = (lane >> 4) * 4;

  // Layer 1: 320 -> 256, relu. Each wave: 64 output cols. H written back into Xs.
  {
    f32x4 acc[4][4];
#pragma unroll
    for (int m = 0; m < 4; ++m)
#pragma unroll
      for (int n = 0; n < 4; ++n)
#pragma unroll
        for (int i = 0; i < 4; ++i) acc[m][n][i] = 0.0f;
    gemm_tile64<10, 4>(Xs, 328, wf + OF_MW1 + (size_t)(w * 4) * 10 * 512, acc, lane);
    __syncthreads();
#pragma unroll
    for (int n = 0; n < 4; ++n) {
      const int col = w * 64 + n * 16 + cw;
      const float bias = mb1[col];
#pragma unroll
      for (int m = 0; m < 4; ++m)
#pragma unroll
        for (int q = 0; q < 4; ++q) {
          const int row = m * 16 + rq + q;
          Xs[row * 328 + col] = f2bf(fmaxf(acc[m][n][q] + bias, 0.0f));
        }
    }
  }
  __syncthreads();

  // Layer 2: 256 -> 256, relu, in-place on Xs.
  {
    f32x4 acc[4][4];
#pragma unroll
    for (int m = 0; m < 4; ++m)
#pragma unroll
      for (int n = 0; n < 4; ++n)
#pragma unroll
        for (int i = 0; i < 4; ++i) acc[m][n][i] = 0.0f;
    gemm_tile64<8, 4>(Xs, 328, wf + OF_MW2 + (size_t)(w * 4) * 8 * 512, acc, lane);
    __syncthreads();
#pragma unroll
    for (int n = 0; n < 4; ++n) {
      const int col = w * 64 + n * 16 + cw;
      const float bias = mb2[col];
#pragma unroll
      for (int m = 0; m < 4; ++m)
#pragma unroll
        for (int q = 0; q < 4; ++q) {
          const int row = m * 16 + rq + q;
          Xs[row * 328 + col] = f2bf(fmaxf(acc[m][n][q] + bias, 0.0f));
        }
    }
  }
  __syncthreads();

  // Layer 3: 256 -> 128.
  {
    f32x4 acc[4][2];
#pragma unroll
    for (int m = 0; m < 4; ++m)
#pragma unroll
      for (int n = 0; n < 2; ++n)
#pragma unroll
        for (int i = 0; i < 4; ++i) acc[m][n][i] = 0.0f;
    gemm_tile64<8, 2>(Xs, 328, wf + OF_MW3 + (size_t)(w * 2) * 8 * 512, acc, lane);

    if constexpr (ATOMIC) {
#pragma unroll
      for (int n = 0; n < 2; ++n) {
        const int col = w * 32 + n * 16 + cw;
        const float bias = mb3[col];
#pragma unroll
        for (int m = 0; m < 4; ++m)
#pragma unroll
          for (int q = 0; q < 4; ++q) {
            const int row = m * 16 + rq + q;
            const float v = acc[m][n][q] + bias;
            unsafeAtomicAdd(&summed[(size_t)vl[2 * row] * 128 + col], v);
            unsafeAtomicAdd(&summed[(size_t)vl[2 * row + 1] * 128 + col], v);
          }
      }
    } else {
      __syncthreads();  // all layer-3 reads of Xs done before overwrite
#pragma unroll
      for (int n = 0; n < 2; ++n) {
        const int col = w * 32 + n * 16 + cw;
        const float bias = mb3[col];
#pragma unroll
        for (int m = 0; m < 4; ++m)
#pragma unroll
          for (int q = 0; q < 4; ++q) {
            const int row = m * 16 + rq + q;
            Xs[row * 328 + col] = f2bf(acc[m][n][q] + bias);
          }
      }
      __syncthreads();
      // Stream the 64x128 bf16 message tile out, fully coalesced.
#pragma unroll
      for (int i = tid; i < 1024; i += 256) {
        const int row = i >> 4;
        const int c = (i & 15) * 8;
        *reinterpret_cast<bf16x8*>(&msgs[(size_t)(e0 + row) * 128 + c]) =
            *reinterpret_cast<const bf16x8*>(&Xs[row * 328 + c]);
      }
    }
  }
}

// Update MLP: 64 nodes per workgroup, 4 waves, single LDS buffer -> 3 blocks/CU.
// attention[n] = ns[n] - ns[n^2048].
// GATHER=true: sum messages via CSR buckets. GATHER=false: read precomputed summed.
template <bool GATHER>
__global__ __launch_bounds__(256, 3) void upd_kernel(
    const float* __restrict__ ns, const float* __restrict__ summed,
    const unsigned short* __restrict__ msgs, const int* __restrict__ cnt,
    const int* __restrict__ eidx, const unsigned short* __restrict__ wf,
    const float* __restrict__ ub1, const float* __restrict__ ub2,
    const float* __restrict__ ub3, float* __restrict__ out) {
  extern __shared__ unsigned short smem[];
  unsigned short* Xs = smem;  // [64][392]; X cols 0..383, then H 0..255

  const int tid = threadIdx.x;
  const int lane = tid & 63;
  const int w = tid >> 6;
  const int n0 = blockIdx.x * 64;

  // Phase 1: node | attention -> Xs; summed read (fallback) or eidx staging (CSR).
  for (int i = tid; i < 1024; i += 256) {
    const int row = i >> 4;
    const int c = (i & 15) * 8;
    const int n = n0 + row;
    const float4* sA = reinterpret_cast<const float4*>(ns + (size_t)n * 128 + c);
    const float4 a0 = sA[0], a1 = sA[1];
    cvt_store8(&Xs[row * 392 + c], a0, a1);
    if constexpr (!GATHER) {
      const float4* sS = reinterpret_cast<const float4*>(summed + (size_t)n * 128 + c);
      cvt_store8(&Xs[row * 392 + 128 + c], sS[0], sS[1]);
    }
    const float4* sP = reinterpret_cast<const float4*>(ns + (size_t)(n ^ 2048) * 128 + c);
    const float4 p0 = sP[0], p1 = sP[1];
    float4 d0, d1;
    d0.x = a0.x - p0.x; d0.y = a0.y - p0.y; d0.z = a0.z - p0.z; d0.w = a0.w - p0.w;
    d1.x = a1.x - p1.x; d1.y = a1.y - p1.y; d1.z = a1.z - p1.z; d1.w = a1.w - p1.w;
    cvt_store8(&Xs[row * 392 + 256 + c], d0, d1);
  }

  if constexpr (GATHER) {
    // Stage this tile's eidx lists into Xs cols 128..255 (64 ints per row).
    for (int i = tid; i < 1024; i += 256) {
      const int row = i >> 4;
      const int q4 = i & 15;
      reinterpret_cast<int4*>(&Xs[row * 392 + 128])[q4] =
          reinterpret_cast<const int4*>(&eidx[(size_t)(n0 + row) * 64])[q4];
    }
    __syncthreads();

    // 4 threads per node, 32 cols each; fp32 accumulate in registers.
    const int nl = tid >> 2;
    const int part = tid & 3;
    const int cn = min(cnt[n0 + nl], 64);
    const int* el = reinterpret_cast<const int*>(&Xs[nl * 392 + 128]);
    float acc[32];
#pragma unroll
    for (int k = 0; k < 32; ++k) acc[k] = 0.0f;
    for (int j = 0; j < cn; ++j) {
      const int e = el[j];
      const bf16x8* mp = reinterpret_cast<const bf16x8*>(&msgs[(size_t)e * 128 + part * 32]);
#pragma unroll
      for (int t = 0; t < 4; ++t) {
        const bf16x8 v = mp[t];
#pragma unroll
        for (int k = 0; k < 8; ++k) acc[t * 8 + k] += bf2f(v[k]);
      }
    }
    __syncthreads();  // all eidx LDS reads done before overwrite
#pragma unroll
    for (int t = 0; t < 4; ++t) {
      union { unsigned short u[8]; bf16x8 v; } o;
#pragma unroll
      for (int k = 0; k < 8; ++k) o.u[k] = f2bf(acc[t * 8 + k]);
      *reinterpret_cast<bf16x8*>(&Xs[nl * 392 + 128 + part * 32 + t * 8]) = o.v;
    }
  }
  __syncthreads();

  const int cw = lane & 15;
  const int rq = (lane >> 4) * 4;

  // Layer 1: 384 -> 256, relu. Each wave: 64 output cols. H back into Xs.
  {
    f32x4 acc[4][4];
#pragma unroll
    for (int m = 0; m < 4; ++m)
#pragma unroll
      for (int n = 0; n < 4; ++n)
#pragma unroll
        for (int i = 0; i < 4; ++i) acc[m][n][i] = 0.0f;
    gemm_tile64<12, 4>(Xs, 392, wf + OF_UW1 + (size_t)(w * 4) * 12 * 512, acc, lane);
    __syncthreads();
#pragma unroll
    for (int n = 0; n < 4; ++n) {
      const int col = w * 64 + n * 16 + cw;
      const float bias = ub1[col];
#pragma unroll
      for (int m = 0; m < 4; ++m)
#pragma unroll
        for (int q = 0; q < 4; ++q) {
          const int row = m * 16 + rq + q;
          Xs[row * 392 + col] = f2bf(fmaxf(acc[m][n][q] + bias, 0.0f));
        }
    }
  }
  __syncthreads();

  // Layer 2: 256 -> 256, relu, in-place on Xs.
  {
    f32x4 acc[4][4];
#pragma unroll
    for (int m = 0; m < 4; ++m)
#pragma unroll
      for (int n = 0; n < 4; ++n)
#pragma unroll
        for (int i = 0; i < 4; ++i) acc[m][n][i] = 0.0f;
    gemm_tile64<8, 4>(Xs, 392, wf + OF_UW2 + (size_t)(w * 4) * 8 * 512, acc, lane);
    __syncthreads();
#pragma unroll
    for (int n = 0; n < 4; ++n) {
      const int col = w * 64 + n * 16 + cw;
      const float bias = ub2[col];
#pragma unroll
      for (int m = 0; m < 4; ++m)
#pragma unroll
        for (int q = 0; q < 4; ++q) {
          const int row = m * 16 + rq + q;
          Xs[row * 392 + col] = f2bf(fmaxf(acc[m][n][q] + bias, 0.0f));
        }
    }
  }
  __syncthreads();

  // Layer 3: 256 -> 128 -> out (fp32). Each wave: 32 output cols.
  {
    f32x4 acc[4][2];
#pragma unroll
    for (int m = 0; m < 4; ++m)
#pragma unroll
      for (int n = 0; n < 2; ++n)
#pragma unroll
        for (int i = 0; i < 4; ++i) acc[m][n][i] = 0.0f;
    gemm_tile64<8, 2>(Xs, 392, wf + OF_UW3 + (size_t)(w * 2) * 8 * 512, acc, lane);
#pragma unroll
    for (int n = 0; n < 2; ++n) {
      const int col = w * 32 + n * 16 + cw;
      const float bias = ub3[col];
#pragma unroll
      for (int m = 0; m < 4; ++m)
#pragma unroll
        for (int q = 0; q < 4; ++q) {
          const int row = m * 16 + rq + q;
          out[(size_t)(n0 + row) * 128 + col] = acc[m][n][q] + bias;
        }
    }
  }
}

extern "C" void kernel_launch(void* const* d_in, const int* in_sizes, int n_in,
                              void* d_out, int out_size, void* d_ws, size_t ws_size,
                              hipStream_t stream) {
  const float* ns   = (const float*)d_in[0];
  const float* edg  = (const float*)d_in[1];
  const int* verts  = (const int*)d_in[2];
  const float* mW1  = (const float*)d_in[3];
  const float* mb1  = (const float*)d_in[4];
  const float* mW2  = (const float*)d_in[5];
  const float* mb2  = (const float*)d_in[6];
  const float* mW3  = (const float*)d_in[7];
  const float* mb3  = (const float*)d_in[8];
  const float* uW1  = (const float*)d_in[9];
  const float* ub1  = (const float*)d_in[10];
  const float* uW2  = (const float*)d_in[11];
  const float* ub2  = (const float*)d_in[12];
  const float* uW3  = (const float*)d_in[13];
  const float* ub3  = (const float*)d_in[14];
  float* out = (float*)d_out;

  const int msg_lds = 64 * 328 * 2 + 128 * 4;  // 42496 B -> 3 blocks/CU
  const int upd_lds = 64 * 392 * 2;            // 50176 B -> 3 blocks/CU

  if (ws_size >= WS_NEED) {
    // CSR path: no fp32 scatter-atomics.
    unsigned short* msgs = (unsigned short*)d_ws;
    int* eidx = (int*)((char*)d_ws + WS_EIDX_OFF);
    int* cnt  = (int*)((char*)d_ws + WS_CNT_OFF);
    unsigned short* wf = (unsigned short*)((char*)d_ws + WS_WF_OFF);

    hipMemsetAsync(cnt, 0, WS_CNT_BYTES, stream);
    prep_weights<<<736, 64, 0, stream>>>(mW1, mW2, mW3, uW1, uW2, uW3, wf);
    fill_csr<<<2 * NEDGES / 256, 256, 0, stream>>>(verts, cnt, eidx);
    msg_kernel<false><<<NEDGES / 64, 256, msg_lds, stream>>>(
        ns, edg, verts, wf, mb1, mb2, mb3, nullptr, msgs);
    upd_kernel<true><<<NNODES / 64, 256, upd_lds, stream>>>(
        ns, nullptr, msgs, cnt, eidx, wf, ub1, ub2, ub3, out);
  } else {
    // Fallback: round-2 atomic path.
    float* summed = (float*)d_ws;
    unsigned short* wf = (unsigned short*)((char*)d_ws + WS_SUMMED_BYTES);

    hipMemsetAsync(summed, 0, WS_SUMMED_BYTES, stream);
    prep_weights<<<736, 64, 0, stream>>>(mW1, mW2, mW3, uW1, uW2, uW3, wf);
    msg_kernel<true><<<NEDGES / 64, 256, msg_lds, stream>>>(
        ns, edg, verts, wf, mb1, mb2, mb3, summed, nullptr);
    upd_kernel<false><<<NNODES / 64, 256, upd_lds, stream>>>(
        ns, summed, nullptr, nullptr, nullptr, wf, ub1, ub2, ub3, out);
  }
}